// Round 8
// baseline (370.004 us; speedup 1.0000x reference)
//
#include <hip/hip_runtime.h>
#include <hip/hip_bf16.h>

#define D 128
#define CAT 640
#define BM 32
#define NG 8               // seed-groups per persistent block
#define W1F_ELEMS 81920    // 20*8*64*8
#define W2F_ELEMS 16384    // 4*8*64*8

typedef __attribute__((ext_vector_type(8))) short bf16x8;
typedef __attribute__((ext_vector_type(4))) float f32x4;

static __device__ __forceinline__ unsigned short f32_to_bf16(float f) {
    unsigned u = __float_as_uint(f);
    unsigned r = u + 0x7FFFu + ((u >> 16) & 1u);   // RNE
    return (unsigned short)(r >> 16);
}

static __device__ __forceinline__ unsigned pack_bf16x2(float a, float b) {
    __hip_bfloat162 h = __float22bfloat162_rn(make_float2(a, b));  // v_cvt_pk_bf16_f32
    return *reinterpret_cast<unsigned*>(&h);
}

// async global->LDS, 16B per lane, wave-uniform LDS base + lane*16
static __device__ __forceinline__ void gload_lds16(const float* g, void* lds) {
    __builtin_amdgcn_global_load_lds(
        (const __attribute__((address_space(1))) void*)g,
        (__attribute__((address_space(3))) void*)lds, 16, 0, 0);
}

// Pack W1 [128][640] and W2 [128][128] (fp32, torch Linear [out,in]) into MFMA
// B-fragment order: (ks, j16, lane, e) = W[j16*16 + (lane&15)][ks*32 + (lane>>4)*8 + e]
__global__ void prep_frags(const float* __restrict__ W1, const float* __restrict__ W2,
                           unsigned short* __restrict__ W1f, unsigned short* __restrict__ W2f) {
    int f = blockIdx.x * 256 + threadIdx.x;
    if (f < W1F_ELEMS) {
        int e = f & 7, l = (f >> 3) & 63, j16 = (f >> 9) & 7, ks = f >> 12;
        int o = j16 * 16 + (l & 15);
        int k = ks * 32 + ((l >> 4) << 3) + e;
        W1f[f] = f32_to_bf16(W1[o * CAT + k]);
    } else if (f < W1F_ELEMS + W2F_ELEMS) {
        int f2 = f - W1F_ELEMS;
        int e = f2 & 7, l = (f2 >> 3) & 63, j16 = (f2 >> 9) & 7, ks = f2 >> 12;
        int o = j16 * 16 + (l & 15);
        int k = ks * 32 + ((l >> 4) << 3) + e;
        W2f[f2] = f32_to_bf16(W2[o * D + k]);
    }
}

// R8: persistent pipeline. 1024 blocks (3/CU), each runs NG=8 seed-groups of
// 32 seeds. GEMM1's K=640 = 5 neighbor-chunks of 32 rows x 128 fp32 (16 KB),
// TRIPLE-buffered via async global_load_lds, issued TWO chunks ahead — the
// in-order vmcnt drain forced by each compute phase's W1-frag loads then
// proves chunk c landed via vmcnt(4) while giving each gather ~2 compute
// phases (>= HBM latency) of cover. The pipeline never drains across group
// boundaries: next group's seeds prefetch during chunk 0, staging bases
// refresh at chunk 3, and the GEMM2 epilogue overlaps the next group's
// first two chunk loads. Per-lane global addrs pre-swizzled (m173) so the
// linear LDS writes land XOR-swizzled for conflict-free ds_read_b128.
__global__ __launch_bounds__(256, 3) void rowmlp_kernel(
    const float* __restrict__ x_rows, const int* __restrict__ seeds,
    const unsigned short* __restrict__ W1f, const float* __restrict__ b1,
    const unsigned short* __restrict__ W2f, const float* __restrict__ b2,
    float* __restrict__ out, int Nrows)
{
    __shared__ __align__(16) unsigned char Ab[3][16384];   // 48 KB staging
    __shared__ __align__(16) unsigned short Hb[16][D];     // 4 KB (half tile)
    __shared__ int sseed[2][BM];

    const int tid = threadIdx.x;
    const int blk = blockIdx.x;
    const int w   = tid >> 6;    // wave: stages rows 8w..8w+7; owns cols 32w..32w+31
    const int l   = tid & 63;
    const int l15 = l & 15;
    const int lhi = l >> 4;

    // fixed staging geometry: instr i covers rows 8w+2i + (l>>5);
    // lane covers 16B chunk (l&31), source chunk pre-swizzled ^(r&7)
    int srow[4], scoff[4], sbase[4];
    #pragma unroll
    for (int i = 0; i < 4; ++i) {
        srow[i]  = 8 * w + 2 * i + (l >> 5);
        scoff[i] = ((l & 31) ^ (srow[i] & 7)) << 2;   // float offset within row
    }

    if (tid < BM) sseed[0][tid] = seeds[(blk * NG) * BM + tid];
    __syncthreads();
    #pragma unroll
    for (int i = 0; i < 4; ++i) sbase[i] = sseed[0][srow[i]];

    const bf16x8* W1v = (const bf16x8*)W1f;
    const bf16x8* W2v = (const bf16x8*)W2f;

#define WAIT4 asm volatile("s_waitcnt vmcnt(4)" ::: "memory")
#define WAIT0 asm volatile("s_waitcnt vmcnt(0)" ::: "memory")
#define BAR   __builtin_amdgcn_s_barrier()

#define ISSUE(NB, DST)                                                         \
    {                                                                          \
        _Pragma("unroll")                                                      \
        for (int i = 0; i < 4; ++i) {                                          \
            int idx = sbase[i] + (NB) - 2;                                     \
            idx = idx < 0 ? 0 : (idx >= Nrows ? Nrows - 1 : idx);              \
            gload_lds16(x_rows + (size_t)idx * D + scoff[i],                   \
                        (void*)((DST) + w * 4096 + i * 1024));                 \
        }                                                                      \
    }

#define COMPUTE(SRC, NB)                                                       \
    {                                                                          \
        const float* buf = (const float*)(SRC);                                \
        _Pragma("unroll")                                                      \
        for (int ks = 0; ks < 4; ++ks) {                                       \
            bf16x8 a[2];                                                       \
            _Pragma("unroll")                                                  \
            for (int m = 0; m < 2; ++m) {                                      \
                const int r = m * 16 + l15;                                    \
                const int s = r & 7;                                           \
                const int cc = ks * 8 + lhi * 2;                               \
                float4 q0 = *(const float4*)(buf + r * 128 + (((cc) ^ s) << 2));     \
                float4 q1 = *(const float4*)(buf + r * 128 + (((cc + 1) ^ s) << 2)); \
                union { unsigned u[4]; bf16x8 v; } pk;                         \
                pk.u[0] = pack_bf16x2(q0.x, q0.y);                             \
                pk.u[1] = pack_bf16x2(q0.z, q0.w);                             \
                pk.u[2] = pack_bf16x2(q1.x, q1.y);                             \
                pk.u[3] = pack_bf16x2(q1.z, q1.w);                             \
                a[m] = pk.v;                                                   \
            }                                                                  \
            _Pragma("unroll")                                                  \
            for (int n = 0; n < 2; ++n) {                                      \
                bf16x8 b = W1v[(((NB) * 4 + ks) * 8 + (w * 2 + n)) * 64 + l];  \
                _Pragma("unroll")                                              \
                for (int m = 0; m < 2; ++m)                                    \
                    acc[m][n] = __builtin_amdgcn_mfma_f32_16x16x32_bf16(a[m], b, acc[m][n], 0, 0, 0); \
            }                                                                  \
        }                                                                      \
    }

    // rotating staging pointers: COMPUTE reads c0, ISSUE writes c2
    unsigned char* c0 = Ab[0];
    unsigned char* c1 = Ab[1];
    unsigned char* c2 = Ab[2];
#define ROT { unsigned char* t = c0; c0 = c1; c1 = c2; c2 = t; }

    // prologue: issue chunks (0,0) and (0,1)
    ISSUE(0, c0)
    ISSUE(1, c1)

    for (int g = 0; g < NG; ++g) {
        f32x4 acc[2][2] = {};

        // ---- j=0
        WAIT4; BAR;
        if (g < NG - 1 && tid < BM)
            sseed[(g + 1) & 1][tid] = seeds[(blk * NG + g + 1) * BM + tid];
        ISSUE(2, c2)
        COMPUTE(c0, 0)
        ROT
        // ---- j=1
        WAIT4; BAR;
        ISSUE(3, c2)
        COMPUTE(c0, 1)
        ROT
        // ---- j=2
        WAIT4; BAR;
        ISSUE(4, c2)
        COMPUTE(c0, 2)
        ROT
        // ---- j=3: refresh bases to next group, issue its chunk 0
        WAIT4; BAR;
        if (g < NG - 1) {
            #pragma unroll
            for (int i = 0; i < 4; ++i) sbase[i] = sseed[(g + 1) & 1][srow[i]];
            ISSUE(0, c2)
        }
        COMPUTE(c0, 3)
        ROT
        // ---- j=4
        if (g < NG - 1) { WAIT4; } else { WAIT0; }
        BAR;
        if (g < NG - 1) ISSUE(1, c2)
        COMPUTE(c0, 4)
        ROT

        // ---- epilogue: bias+ReLU -> Hb (16-row half) -> GEMM2 -> store, x2
        const size_t obase = (size_t)(blk * NG + g) * BM;
        #pragma unroll
        for (int ph = 0; ph < 2; ++ph) {
            #pragma unroll
            for (int n = 0; n < 2; ++n) {
                const int col = w * 32 + n * 16 + l15;
                const float bias = b1[col];
                #pragma unroll
                for (int r = 0; r < 4; ++r) {
                    const int row = lhi * 4 + r;   // C/D: col=lane&15, row=(lane>>4)*4+reg
                    float v = acc[ph][n][r] + bias;
                    v = v > 0.f ? v : 0.f;
                    Hb[row][col ^ ((row & 7) << 3)] = f32_to_bf16(v);
                }
            }
            __syncthreads();
            f32x4 acc2[2] = {};
            #pragma unroll
            for (int ks = 0; ks < 4; ++ks) {
                bf16x8 a2 = *(const bf16x8*)(&Hb[l15][(ks * 32 + lhi * 8) ^ ((l15 & 7) << 3)]);
                #pragma unroll
                for (int n = 0; n < 2; ++n) {
                    bf16x8 bb = W2v[(ks * 8 + w * 2 + n) * 64 + l];
                    acc2[n] = __builtin_amdgcn_mfma_f32_16x16x32_bf16(a2, bb, acc2[n], 0, 0, 0);
                }
            }
            #pragma unroll
            for (int n = 0; n < 2; ++n) {
                const int col = w * 32 + n * 16 + l15;
                const float bias = b2[col];
                #pragma unroll
                for (int r = 0; r < 4; ++r)
                    out[(obase + ph * 16 + lhi * 4 + r) * D + col] = acc2[n][r] + bias;
            }
            if (ph == 0) __syncthreads();   // GEMM2-A reads done before Hb-B writes
        }
    }
#undef ISSUE
#undef COMPUTE
#undef ROT
#undef WAIT4
#undef WAIT0
#undef BAR
}

extern "C" void kernel_launch(void* const* d_in, const int* in_sizes, int n_in,
                              void* d_out, int out_size, void* d_ws, size_t ws_size,
                              hipStream_t stream) {
    const float* x_rows = (const float*)d_in[0];
    const int*   seeds  = (const int*)d_in[1];
    const float* W1     = (const float*)d_in[2];
    const float* b1     = (const float*)d_in[3];
    const float* W2     = (const float*)d_in[4];
    const float* b2     = (const float*)d_in[5];
    float* out = (float*)d_out;

    int Nrows = in_sizes[0] / D;
    int B = in_sizes[1];

    unsigned short* W1f = (unsigned short*)d_ws;
    unsigned short* W2f = W1f + W1F_ELEMS;

    prep_frags<<<(W1F_ELEMS + W2F_ELEMS + 255) / 256, 256, 0, stream>>>(W1, W2, W1f, W2f);
    int nblocks = B / (NG * BM);   // 1024
    rowmlp_kernel<<<nblocks, 256, 0, stream>>>(x_rows, seeds, W1f, b1, W2f, b2, out, Nrows);
}

// Round 9
// 208.513 us; speedup vs baseline: 1.7745x; 1.7745x over previous
//
#include <hip/hip_runtime.h>
#include <hip/hip_bf16.h>

#define D 128
#define CAT 640
#define BM 32
#define W1F_ELEMS 81920    // 20*8*64*8
#define W2F_ELEMS 16384    // 4*8*64*8

typedef __attribute__((ext_vector_type(8))) short bf16x8;
typedef __attribute__((ext_vector_type(4))) float f32x4;

static __device__ __forceinline__ unsigned short f32_to_bf16(float f) {
    unsigned u = __float_as_uint(f);
    unsigned r = u + 0x7FFFu + ((u >> 16) & 1u);   // RNE
    return (unsigned short)(r >> 16);
}

static __device__ __forceinline__ unsigned pack_bf16x2(float a, float b) {
    __hip_bfloat162 h = __float22bfloat162_rn(make_float2(a, b));  // v_cvt_pk_bf16_f32
    return *reinterpret_cast<unsigned*>(&h);
}

// async global->LDS, 16B per lane, wave-uniform LDS base + lane*16
static __device__ __forceinline__ void gload_lds16(const float* g, void* lds) {
    __builtin_amdgcn_global_load_lds(
        (const __attribute__((address_space(1))) void*)g,
        (__attribute__((address_space(3))) void*)lds, 16, 0, 0);
}

// Pack W1 [128][640] and W2 [128][128] (fp32, torch Linear [out,in]) into MFMA
// B-fragment order: (ks, j16, lane, e) = W[j16*16 + (lane&15)][ks*32 + (lane>>4)*8 + e]
__global__ void prep_frags(const float* __restrict__ W1, const float* __restrict__ W2,
                           unsigned short* __restrict__ W1f, unsigned short* __restrict__ W2f) {
    int f = blockIdx.x * 256 + threadIdx.x;
    if (f < W1F_ELEMS) {
        int e = f & 7, l = (f >> 3) & 63, j16 = (f >> 9) & 7, ks = f >> 12;
        int o = j16 * 16 + (l & 15);
        int k = ks * 32 + ((l >> 4) << 3) + e;
        W1f[f] = f32_to_bf16(W1[o * CAT + k]);
    } else if (f < W1F_ELEMS + W2F_ELEMS) {
        int f2 = f - W1F_ELEMS;
        int e = f2 & 7, l = (f2 >> 3) & 63, j16 = (f2 >> 9) & 7, ks = f2 >> 12;
        int o = j16 * 16 + (l & 15);
        int k = ks * 32 + ((l >> 4) << 3) + e;
        W2f[f2] = f32_to_bf16(W2[o * D + k]);
    }
}

// R9: R7's shape (8192 blocks, 5 neighbor-chunks, LDS double-buffer,
// async global_load_lds) with two measured fixes:
//  (1) FRAGMENT-LINEAR A staging: chunk layout [m][ks][h][64 lanes][16B] —
//      the wave-linear global_load_lds write IS the MFMA fragment layout, and
//      GEMM1 ds_read_b128 is lane-stride-16 linear => zero bank conflicts
//      (R8 measured 1.15e7 conflict-cycles with the swizzled row-major tile).
//  (2) W1 fragments prefetched into double-buffered REGISTERS so COMPUTE has
//      no global loads: the only vmem wait is the phase-top vmcnt(0), giving
//      each gather a full compute phase of latency cover (R8 showed W1 loads
//      pollute the in-order vmcnt queue and force early gather drains).
// LDS 36.3 KB -> 4 blocks/CU = 16 waves/CU.
__global__ __launch_bounds__(256, 4) void rowmlp_kernel(
    const float* __restrict__ x_rows, const int* __restrict__ seeds,
    const unsigned short* __restrict__ W1f, const float* __restrict__ b1,
    const unsigned short* __restrict__ W2f, const float* __restrict__ b2,
    float* __restrict__ out, int Nrows)
{
    __shared__ __align__(16) unsigned char Ab[2][16384];   // fragment-linear staging
    __shared__ __align__(16) unsigned short Hb[16][D];     // 4 KB half tile
    __shared__ int sseed[BM];

    const int tid = threadIdx.x;
    const int blk = blockIdx.x;
    const int w   = tid >> 6;    // wave 0..3
    const int l   = tid & 63;
    const int l15 = l & 15;
    const int lhi = l >> 4;

    if (tid < BM) sseed[tid] = seeds[blk * BM + tid];
    __syncthreads();

    // staging: wave w owns fragment-slots i = 4w+t, t=0..3, where
    // i = m*8 + ks*2 + h  (m = w>>1, ks = (w&1)*2 + (t>>1), h = t&1).
    // lane l loads floats [ks*32 + lhi*8 + h*4, +4) of row seed[m*16+l15]+j-2.
    const int sb  = sseed[((w >> 1) << 4) + l15];   // this wave's staging seed
    const int ksb = (w & 1) * 2;

    const bf16x8* W1v = (const bf16x8*)W1f;
    const bf16x8* W2v = (const bf16x8*)W2f;

#define WAIT0 asm volatile("s_waitcnt vmcnt(0)" ::: "memory")
#define BAR   __builtin_amdgcn_s_barrier()

#define ISSUE(J, BUF)                                                          \
    {                                                                          \
        int idx = sb + (J) - 2;                                                \
        idx = idx < 0 ? 0 : (idx >= Nrows ? Nrows - 1 : idx);                  \
        const float* rp = x_rows + (size_t)idx * D + lhi * 8;                  \
        unsigned char* dst = Ab[BUF] + w * 4096;                               \
        gload_lds16(rp + (ksb + 0) * 32 + 0, dst + 0 * 1024);                  \
        gload_lds16(rp + (ksb + 0) * 32 + 4, dst + 1 * 1024);                  \
        gload_lds16(rp + (ksb + 1) * 32 + 0, dst + 2 * 1024);                  \
        gload_lds16(rp + (ksb + 1) * 32 + 4, dst + 3 * 1024);                  \
    }

#define LOADW1(J, RB)                                                          \
    {                                                                          \
        _Pragma("unroll")                                                      \
        for (int ks = 0; ks < 4; ++ks)                                         \
            _Pragma("unroll")                                                  \
            for (int n = 0; n < 2; ++n)                                        \
                w1r[RB][ks][n] = W1v[(((J) * 4 + ks) * 8 + (w * 2 + n)) * 64 + l]; \
    }

#define COMPUTE(BUF, RB)                                                       \
    {                                                                          \
        const float* fb = (const float*)Ab[BUF];                               \
        _Pragma("unroll")                                                      \
        for (int ks = 0; ks < 4; ++ks) {                                       \
            bf16x8 a[2];                                                       \
            _Pragma("unroll")                                                  \
            for (int m = 0; m < 2; ++m) {                                      \
                float4 q0 = *(const float4*)(fb + (m * 8 + ks * 2 + 0) * 256 + l * 4); \
                float4 q1 = *(const float4*)(fb + (m * 8 + ks * 2 + 1) * 256 + l * 4); \
                union { unsigned u[4]; bf16x8 v; } pk;                         \
                pk.u[0] = pack_bf16x2(q0.x, q0.y);                             \
                pk.u[1] = pack_bf16x2(q0.z, q0.w);                             \
                pk.u[2] = pack_bf16x2(q1.x, q1.y);                             \
                pk.u[3] = pack_bf16x2(q1.z, q1.w);                             \
                a[m] = pk.v;                                                   \
            }                                                                  \
            _Pragma("unroll")                                                  \
            for (int n = 0; n < 2; ++n)                                        \
                _Pragma("unroll")                                              \
                for (int m = 0; m < 2; ++m)                                    \
                    acc[m][n] = __builtin_amdgcn_mfma_f32_16x16x32_bf16(       \
                        a[m], w1r[RB][ks][n], acc[m][n], 0, 0, 0);             \
        }                                                                      \
    }

    bf16x8 w1r[2][4][2];
    f32x4 acc[2][2] = {};

    // prologue: W1 regs for chunk 0, gather chunk 0
    LOADW1(0, 0)
    ISSUE(0, 0)

    // j=0
    WAIT0; BAR;
    LOADW1(1, 1) ISSUE(1, 1)
    COMPUTE(0, 0)
    // j=1
    WAIT0; BAR;
    LOADW1(2, 0) ISSUE(2, 0)
    COMPUTE(1, 1)
    // j=2
    WAIT0; BAR;
    LOADW1(3, 1) ISSUE(3, 1)
    COMPUTE(0, 0)
    // j=3
    WAIT0; BAR;
    LOADW1(4, 0) ISSUE(4, 0)
    COMPUTE(1, 1)
    // j=4
    WAIT0; BAR;
    COMPUTE(0, 0)

    // ---- epilogue: W2 regs (w1r dead now), then 2x (Hb half -> GEMM2 -> store)
    bf16x8 w2r[4][2];
    #pragma unroll
    for (int ks = 0; ks < 4; ++ks)
        #pragma unroll
        for (int n = 0; n < 2; ++n)
            w2r[ks][n] = W2v[(ks * 8 + (w * 2 + n)) * 64 + l];

    const size_t obase = (size_t)blk * BM;
    #pragma unroll
    for (int ph = 0; ph < 2; ++ph) {
        #pragma unroll
        for (int n = 0; n < 2; ++n) {
            const int col = w * 32 + n * 16 + l15;
            const float bias = b1[col];
            #pragma unroll
            for (int r = 0; r < 4; ++r) {
                const int row = lhi * 4 + r;   // C/D: col=lane&15, row=(lane>>4)*4+reg
                float v = acc[ph][n][r] + bias;
                v = v > 0.f ? v : 0.f;
                Hb[row][col ^ (row << 3)] = f32_to_bf16(v);   // 4-bit row swizzle
            }
        }
        __syncthreads();
        f32x4 acc2[2] = {};
        #pragma unroll
        for (int ks = 0; ks < 4; ++ks) {
            bf16x8 a2 = *(const bf16x8*)(&Hb[l15][(ks * 32 + lhi * 8) ^ (l15 << 3)]);
            #pragma unroll
            for (int n = 0; n < 2; ++n)
                acc2[n] = __builtin_amdgcn_mfma_f32_16x16x32_bf16(a2, w2r[ks][n], acc2[n], 0, 0, 0);
        }
        #pragma unroll
        for (int n = 0; n < 2; ++n) {
            const int col = w * 32 + n * 16 + l15;
            const float bias = b2[col];
            #pragma unroll
            for (int r = 0; r < 4; ++r)
                out[(obase + ph * 16 + lhi * 4 + r) * D + col] = acc2[n][r] + bias;
        }
        if (ph == 0) __syncthreads();   // GEMM2-A reads done before next Hb writes
    }
#undef ISSUE
#undef LOADW1
#undef COMPUTE
#undef WAIT0
#undef BAR
}

extern "C" void kernel_launch(void* const* d_in, const int* in_sizes, int n_in,
                              void* d_out, int out_size, void* d_ws, size_t ws_size,
                              hipStream_t stream) {
    const float* x_rows = (const float*)d_in[0];
    const int*   seeds  = (const int*)d_in[1];
    const float* W1     = (const float*)d_in[2];
    const float* b1     = (const float*)d_in[3];
    const float* W2     = (const float*)d_in[4];
    const float* b2     = (const float*)d_in[5];
    float* out = (float*)d_out;

    int Nrows = in_sizes[0] / D;
    int B = in_sizes[1];

    unsigned short* W1f = (unsigned short*)d_ws;
    unsigned short* W2f = W1f + W1F_ELEMS;

    prep_frags<<<(W1F_ELEMS + W2F_ELEMS + 255) / 256, 256, 0, stream>>>(W1, W2, W1f, W2f);
    rowmlp_kernel<<<B / BM, 256, 0, stream>>>(x_rows, seeds, W1f, b1, W2f, b2, out, Nrows);
}